// Round 10
// baseline (321.933 us; speedup 1.0000x reference)
//
#include <hip/hip_runtime.h>

// SpeakerCrossAttention on MI355X (gfx950) — v10: fused single-pass pipeline.
// B=16, D=512, T=8192, S=256. f32 in/out; GEMM in bf16 MFMA.
//
//  prep : per-batch chain -> attnn/biasb; W1f -> bf16 PERMUTED (v8/v9-verified)
//  main : 256 persistent blocks x 1024 thr; 16 tiles of 32t per block.
//    per tile: [bar; vmcnt(16) -> own DMAs done] -> convert F[P]->Bt (LDS->LDS,
//    wave-local) -> [bar] -> GEMM (af-waits see no in-flight DMA) -> issue
//    DMA(j+1)->F[P^1] -> alpha (gpart aliased in dead F[P]) -> blend (plain
//    stores, 16/thread). Total HBM traffic = 512 MB (features once, out once).

typedef __attribute__((ext_vector_type(8))) short short8;     // 8 bf16 = 16B
typedef __attribute__((ext_vector_type(4))) unsigned short ushort4v;
typedef __attribute__((ext_vector_type(4))) float f32x4;

#define T_DIM 8192
#define D_DIM 512

__device__ __forceinline__ unsigned short f2bf(float x) {  // RTNE f32 -> bf16
  unsigned u = __builtin_bit_cast(unsigned, x);
  u = (u + 0x7fffu + ((u >> 16) & 1u)) >> 16;
  return (unsigned short)u;
}
__device__ __forceinline__ float bf2f(unsigned short h) {
  return __builtin_bit_cast(float, ((unsigned)h) << 16);
}
__device__ __forceinline__ void dma16(const void* g, void* l) {
  __builtin_amdgcn_global_load_lds(
      (const __attribute__((address_space(1))) void*)g,
      (__attribute__((address_space(3))) void*)l, 16, 0, 0);
}

// ---------------- prep kernel (v8/v9-verified) ----------------
__global__ __launch_bounds__(512) void prep_kernel(
    const float* __restrict__ spk_in, const float* __restrict__ Wsp,
    const float* __restrict__ bsp,    const float* __restrict__ Wv,
    const float* __restrict__ bv,     const float* __restrict__ Wo,
    const float* __restrict__ bo,     const float* __restrict__ gma,
    const float* __restrict__ bta,    const float* __restrict__ Wg1,
    const float* __restrict__ bg1,
    float* __restrict__ attnn, float* __restrict__ biasb,
    unsigned short* __restrict__ w1fx)
{
  int tid = threadIdx.x;
  int blk = blockIdx.x;

  if (blk >= 16) {                    // ---- W1f -> bf16, permuted ----
    #pragma unroll
    for (int i = 0; i < 4; ++i) {
      int idx = (blk - 16) * 2048 + i * 512 + tid;
      int e  = idx & 7;
      int l  = (idx >> 3) & 63;
      int ni = (idx >> 9) & 1;
      int kk = (idx >> 10) & 3;
      int c  = (idx >> 12) & 3;
      int w  = (idx >> 14) & 15;
      int n = w * 32 + ni * 16 + (l & 15);
      int d = c * 128 + kk * 32 + (l >> 4) * 8 + e;
      w1fx[idx] = f2bf(Wg1[n * 1024 + d]);
    }
    return;
  }

  int b = blk;
  __shared__ __attribute__((aligned(16))) float s_spk[256];
  __shared__ __attribute__((aligned(16))) float s_x[512];
  __shared__ __attribute__((aligned(16))) float s_y[512];
  __shared__ float red[512];

  float se = (tid < 256) ? spk_in[b * 256 + tid] : 0.f;
  red[tid] = se * se;
  __syncthreads();
  for (int s = 256; s > 0; s >>= 1) {
    if (tid < s) red[tid] += red[tid + s];
    __syncthreads();
  }
  float scale = 1.f / fmaxf(sqrtf(red[0]), 1e-12f);
  if (tid < 256) s_spk[tid] = se * scale;
  __syncthreads();

  {
    const float* wr = Wsp + (size_t)tid * 256;
    f32x4 a4 = {0.f, 0.f, 0.f, 0.f};
    #pragma unroll 8
    for (int s2 = 0; s2 < 256; s2 += 4)
      a4 += (*(const f32x4*)(wr + s2)) * (*(const f32x4*)(s_spk + s2));
    s_x[tid] = a4[0] + a4[1] + a4[2] + a4[3] + bsp[tid];
  }
  __syncthreads();

  {
    const float* wr = Wv + (size_t)tid * 512;
    f32x4 a4 = {0.f, 0.f, 0.f, 0.f};
    #pragma unroll 8
    for (int s2 = 0; s2 < 512; s2 += 4)
      a4 += (*(const f32x4*)(wr + s2)) * (*(const f32x4*)(s_x + s2));
    s_y[tid] = a4[0] + a4[1] + a4[2] + a4[3] + bv[tid];
  }
  __syncthreads();

  float attnv;
  {
    const float* wr = Wo + (size_t)tid * 512;
    f32x4 a4 = {0.f, 0.f, 0.f, 0.f};
    #pragma unroll 8
    for (int s2 = 0; s2 < 512; s2 += 4)
      a4 += (*(const f32x4*)(wr + s2)) * (*(const f32x4*)(s_y + s2));
    attnv = a4[0] + a4[1] + a4[2] + a4[3] + bo[tid];
  }

  red[tid] = attnv;
  __syncthreads();
  for (int s = 256; s > 0; s >>= 1) {
    if (tid < s) red[tid] += red[tid + s];
    __syncthreads();
  }
  float mu = red[0] * (1.f / 512.f);
  __syncthreads();
  float dv = attnv - mu;
  red[tid] = dv * dv;
  __syncthreads();
  for (int s = 256; s > 0; s >>= 1) {
    if (tid < s) red[tid] += red[tid + s];
    __syncthreads();
  }
  float var = red[0] * (1.f / 512.f);
  float an = dv * rsqrtf(var + 1e-5f) * gma[tid] + bta[tid];
  s_x[tid] = an;
  attnn[b * 512 + tid] = an;
  __syncthreads();

  {
    const float* wr = Wg1 + (size_t)tid * 1024 + 512;
    f32x4 a4 = {0.f, 0.f, 0.f, 0.f};
    #pragma unroll 8
    for (int s2 = 0; s2 < 512; s2 += 4)
      a4 += (*(const f32x4*)(wr + s2)) * (*(const f32x4*)(s_x + s2));
    biasb[b * 512 + tid] = a4[0] + a4[1] + a4[2] + a4[3] + bg1[tid];
  }
}

// ---------------- main kernel ----------------
// 256 blocks x 1024 thr (16 waves). b = blk>>4, tseg = blk&15 -> 16 tiles of 32t.
// LDS: F dbuf 2x64KB (raw f32, DMA'd) + Bt 32KB (bf16 swizzled) = 160KB exactly.
// gpart (2KB) + alpha (128B) aliased into the dead F[P] half after convert.
__global__ __launch_bounds__(1024) void main_kernel(
    const float* __restrict__ feat, const unsigned short* __restrict__ w1fx,
    const float* __restrict__ attnn, const float* __restrict__ biasb,
    const float* __restrict__ wg2p,  const float* __restrict__ bg2p,
    float* __restrict__ out)
{
  __shared__ __attribute__((aligned(16))) float F[2][16384];         // 128 KB
  __shared__ __attribute__((aligned(16))) unsigned short Bt[16384];  // 32 KB

  int tid = threadIdx.x;
  int l = tid & 63, w = tid >> 6;
  int b = blockIdx.x >> 4, tseg = blockIdx.x & 15;
  int t0base = tseg * 512;
  const char* featb = (const char*)(feat + (size_t)b * D_DIM * T_DIM);
  char* Fc = (char*)F;
  char* Bc = (char*)Bt;

  int a3 = l >> 3;                 // 0..7 : d-offset within DMA block
  int tperm = (l & 7) ^ a3;        // XOR'd t-quad (bank-spread for convert reads)
  int g = l >> 4, cc = l & 15;     // MFMA lane coords (v1/v9-verified)
  int xsw = (cc & 7) << 4;

  // ---- prologue: per-thread constants into registers (no LDS) ----
  float bia[2][4], ww2[2][4];
  #pragma unroll
  for (int ni = 0; ni < 2; ++ni)
    #pragma unroll
    for (int rr = 0; rr < 4; ++rr) {
      int n = w * 32 + ni * 16 + g * 4 + rr;
      bia[ni][rr] = biasb[b * 512 + n];
      ww2[ni][rr] = wg2p[n];
    }
  int tl = tid & 31, dgb = tid >> 5;   // blend coords: t row, d-group (16 d)
  f32x4 att[4];
  #pragma unroll
  for (int h = 0; h < 4; ++h)
    att[h] = *(const f32x4*)(attnn + b * 512 + dgb * 16 + h * 4);
  float bg2v = bg2p[0];

  // DMA: wave w pulls d in [32w,32w+32) x 32 t as 4 instrs of 64 lanes x 16B.
  // lane l, instr q: d = 32w+8q+a3, t-quad = tperm -> global 128B-contiguous
  // segments per 8 lanes; LDS block (w*4+q)*1024 linear.
#define DMA(J) do {                                                         \
    _Pragma("unroll")                                                       \
    for (int q_ = 0; q_ < 4; ++q_) {                                        \
      int d_ = w * 32 + q_ * 8 + a3;                                        \
      dma16(featb + (((size_t)d_) << 15) +                                  \
                ((size_t)(t0base + (J) * 32) << 2) + tperm * 16,            \
            Fc + (((J) & 1) << 16) + (w * 4 + q_) * 1024);                  \
    }                                                                       \
    __builtin_amdgcn_sched_barrier(0);                                      \
  } while (0)

  DMA(0);

  const unsigned short* apw = w1fx + w * 16384;
  int dq = w * 8 + a3;             // convert d-quad (== tid>>3)
  int tqc = l & 7;                 // convert t-quad (== tid&7)

  #pragma unroll 1
  for (int j = 0; j < 16; ++j) {
    int P = j & 1;
    char* FP = Fc + (P << 16);
    float* gp  = (float*)FP;         // 16 waves x 32 t partials (aliased)
    float* als = (float*)(FP + 2048);// 32 alpha values (aliased)

    // top: block-wide LDS quiesce (prior blend/alpha reads), then own-DMA wait
    asm volatile("s_waitcnt lgkmcnt(0)" ::: "memory");
    __builtin_amdgcn_s_barrier();
    if (j == 0) asm volatile("s_waitcnt vmcnt(0)" ::: "memory");
    else        asm volatile("s_waitcnt vmcnt(16)" ::: "memory");
    __builtin_amdgcn_sched_barrier(0);

    // ---- convert: F[P] (wave-local) -> Bt bf16 swizzled [t][d] ----
    {
      f32x4 v[4];
      #pragma unroll
      for (int i = 0; i < 4; ++i) {
        int d = dq * 4 + i;
        int fb_ = ((d >> 3) << 10) + (((d & 7) * 8 + (tqc ^ (d & 7))) << 4);
        v[i] = *(const f32x4*)(FP + fb_);      // feat[d][t0+tqc*4 .. +3]
      }
      #pragma unroll
      for (int ii = 0; ii < 4; ++ii) {
        int t = tqc * 4 + ii;
        ushort4v wv;
        wv[0] = f2bf(v[0][ii]); wv[1] = f2bf(v[1][ii]);
        wv[2] = f2bf(v[2][ii]); wv[3] = f2bf(v[3][ii]);
        *(ushort4v*)(Bc + (t << 10) + ((dq * 8) ^ ((t & 7) << 4))) = wv;
      }
    }
    asm volatile("s_waitcnt lgkmcnt(0)" ::: "memory");
    __builtin_amdgcn_s_barrier();
    __builtin_amdgcn_sched_barrier(0);

    // ---- GEMM: wave w -> n in [32w,32w+32), t in [0,32) ----
    f32x4 acc[2][2];
    #pragma unroll
    for (int i = 0; i < 2; ++i)
      #pragma unroll
      for (int t = 0; t < 2; ++t)
        acc[i][t] = (f32x4){0.f, 0.f, 0.f, 0.f};

    #pragma unroll 4
    for (int kk = 0; kk < 16; ++kk) {
      short8 af0 = *(const short8*)(apw + (kk * 2 + 0) * 512 + l * 8);
      short8 af1 = *(const short8*)(apw + (kk * 2 + 1) * 512 + l * 8);
      short8 bf0 = *(const short8*)(Bc + (cc << 10) + ((kk * 64 + g * 16) ^ xsw));
      short8 bf1 = *(const short8*)(Bc + ((16 + cc) << 10) + ((kk * 64 + g * 16) ^ xsw));
      acc[0][0] = __builtin_amdgcn_mfma_f32_16x16x32_bf16(af0, bf0, acc[0][0], 0, 0, 0);
      acc[0][1] = __builtin_amdgcn_mfma_f32_16x16x32_bf16(af0, bf1, acc[0][1], 0, 0, 0);
      acc[1][0] = __builtin_amdgcn_mfma_f32_16x16x32_bf16(af1, bf0, acc[1][0], 0, 0, 0);
      acc[1][1] = __builtin_amdgcn_mfma_f32_16x16x32_bf16(af1, bf1, acc[1][1], 0, 0, 0);
    }
    __builtin_amdgcn_sched_barrier(0);

    // ---- issue next tile's DMA (after GEMM: af-waits never gate it) ----
    if (j < 15) DMA(j + 1);

    // ---- alpha: p[tg] over this wave's 32 n; cross-wave via gpart in F[P] ----
    float p0 = 0.f, p1 = 0.f;
    #pragma unroll
    for (int ni = 0; ni < 2; ++ni) {
      #pragma unroll
      for (int rr = 0; rr < 4; ++rr) {
        p0 += fmaxf(acc[ni][0][rr] + bia[ni][rr], 0.f) * ww2[ni][rr];
        p1 += fmaxf(acc[ni][1][rr] + bia[ni][rr], 0.f) * ww2[ni][rr];
      }
    }
    p0 += __shfl_xor(p0, 16); p0 += __shfl_xor(p0, 32);
    p1 += __shfl_xor(p1, 16); p1 += __shfl_xor(p1, 32);
    if (l < 16) {
      gp[w * 32 + l] = p0;
      gp[w * 32 + 16 + l] = p1;
    }
    asm volatile("s_waitcnt lgkmcnt(0)" ::: "memory");
    __builtin_amdgcn_s_barrier();
    if (tid < 32) {
      float gs = bg2v;
      #pragma unroll
      for (int w2 = 0; w2 < 16; ++w2) gs += gp[w2 * 32 + tid];
      als[tid] = 1.f / (1.f + expf(-gs));
    }
    asm volatile("s_waitcnt lgkmcnt(0)" ::: "memory");
    __builtin_amdgcn_s_barrier();

    // ---- blend: out[b,d,t] = a*f + (1-a)*attn_n[d]; 16 plain stores ----
    {
      float al = als[tl], om = 1.f - al;
      float* op = out + (size_t)b * D_DIM * T_DIM + t0base + j * 32 + tl;
      int rbase = tl << 10, rsw = (tl & 7) << 4;
      #pragma unroll
      for (int h = 0; h < 2; ++h) {
        short8 fv = *(const short8*)(Bc + rbase + ((dgb * 32 + h * 16) ^ rsw));
        int d0 = dgb * 16 + h * 8;
        #pragma unroll
        for (int e = 0; e < 8; ++e) {
          float an = att[(h * 8 + e) >> 2][(h * 8 + e) & 3];
          op[(size_t)(d0 + e) * T_DIM] = al * bf2f((unsigned short)fv[e]) + om * an;
        }
      }
    }
  }
#undef DMA
}

extern "C" void kernel_launch(void* const* d_in, const int* in_sizes, int n_in,
                              void* d_out, int out_size, void* d_ws, size_t ws_size,
                              hipStream_t stream) {
  const float* features = (const float*)d_in[0];
  const float* spk      = (const float*)d_in[1];
  const float* Wsp      = (const float*)d_in[2];
  const float* bsp      = (const float*)d_in[3];
  const float* Wv       = (const float*)d_in[4];
  const float* bv       = (const float*)d_in[5];
  const float* Wo       = (const float*)d_in[6];
  const float* bo       = (const float*)d_in[7];
  const float* gma      = (const float*)d_in[8];
  const float* bta      = (const float*)d_in[9];
  const float* Wg1      = (const float*)d_in[10];
  const float* bg1      = (const float*)d_in[11];
  const float* Wg2      = (const float*)d_in[12];
  const float* bg2      = (const float*)d_in[13];
  float* out = (float*)d_out;

  // ws: attnn[8192] f32 | biasb[8192] f32 | w1fx[262144] bf16 (permuted)
  float* attnn = (float*)d_ws;
  float* biasb = attnn + 8192;
  unsigned short* w1fx = (unsigned short*)(biasb + 8192);

  prep_kernel<<<144, 512, 0, stream>>>(spk, Wsp, bsp, Wv, bv, Wo, bo, gma, bta,
                                       Wg1, bg1, attnn, biasb, w1fx);
  main_kernel<<<256, 1024, 0, stream>>>(features, w1fx, attnn, biasb, Wg2, bg2, out);
}